// Round 6
// baseline (285.177 us; speedup 1.0000x reference)
//
#include <hip/hip_runtime.h>
#include <hip/hip_bf16.h>
#include <math.h>

#define B_ 2
#define S_ 2048
#define D_ 1024
#define H_ 16
#define HD_ 64

typedef short bf16x8 __attribute__((ext_vector_type(8)));
typedef short bf16x4 __attribute__((ext_vector_type(4)));
typedef float f32x4 __attribute__((ext_vector_type(4)));

#define MFMA32(a, b, c) __builtin_amdgcn_mfma_f32_16x16x32_bf16(a, b, c, 0, 0, 0)
#define MFMA16(a, b, c) __builtin_amdgcn_mfma_f32_16x16x16bf16_1k(a, b, c, 0, 0, 0)

static __device__ __forceinline__ unsigned short f2bf(float f) {
    union { float f; unsigned u; } v = {f};
    return (unsigned short)((v.u + 0x7fffu + ((v.u >> 16) & 1u)) >> 16);
}

// pack two floats -> packed bf16 pair (low = a), via v_cvt_pk_bf16_f32
static __device__ __forceinline__ unsigned pk2bf(float a, float b) {
    __hip_bfloat162 h = __float22bfloat162_rn(make_float2(a, b));
    unsigned r;
    __builtin_memcpy(&r, &h, 4);
    return r;
}

static __device__ __forceinline__ void gl2lds16(const void* g, void* l) {
    __builtin_amdgcn_global_load_lds((const __attribute__((address_space(1))) unsigned int*)g,
                                     (__attribute__((address_space(3))) unsigned int*)l,
                                     16, 0, 0);
}

// ---------------------------------------------------------------------------
// fused fp32 -> bf16 convert for all three inputs (RNE)
// ---------------------------------------------------------------------------
__global__ __launch_bounds__(256) void cvt_all(const float* __restrict__ x,
                                               const float* __restrict__ wq,
                                               const float* __restrict__ wo,
                                               unsigned short* __restrict__ xb,
                                               unsigned short* __restrict__ wqb,
                                               unsigned short* __restrict__ wob) {
    const int N0 = 1048576, N1 = 786432, N2 = 262144;  // float4 counts
    int stride = gridDim.x * blockDim.x;
    for (int i = blockIdx.x * blockDim.x + threadIdx.x; i < N0 + N1 + N2; i += stride) {
        const float4* src; ushort4* dst; int j;
        if (i < N0)            { src = (const float4*)x;  dst = (ushort4*)xb;  j = i; }
        else if (i < N0 + N1)  { src = (const float4*)wq; dst = (ushort4*)wqb; j = i - N0; }
        else                   { src = (const float4*)wo; dst = (ushort4*)wob; j = i - N0 - N1; }
        float4 v = src[j];
        ushort4 o;
        o.x = f2bf(v.x); o.y = f2bf(v.y); o.z = f2bf(v.z); o.w = f2bf(v.w);
        dst[j] = o;
    }
}

// ---------------------------------------------------------------------------
// bf16 NT GEMM, m97-style: global_load_lds(16B) staging, BM=128, BK=32,
// 256 threads. BN=128: waves 2x2 (64x64 each). BN=64: waves 4x1 (32x64).
// ---------------------------------------------------------------------------
template <int BN>
__global__ __launch_bounds__(256) void gemm_nt_b(const unsigned short* __restrict__ A,
                                                 const unsigned short* __restrict__ Bm,
                                                 void* __restrict__ Cout,
                                                 int M, int N, int K, int c_bf16) {
    constexpr int BM = 128, BK = 32;
    constexpr int MI = (BN == 128) ? 4 : 2;
    constexpr int NI = 4;
    constexpr int SEGS = (BM + BN) / 16;
    __shared__ unsigned short As[BM * BK];
    __shared__ unsigned short Bs[BN * BK];

    const int tid = threadIdx.x;
    const int wave = tid >> 6, lane = tid & 63;
    const int m16 = lane & 15, quad = lane >> 4;
    const int wrow = (BN == 128) ? (wave >> 1) * 64 : wave * 32;
    const int wcol = (BN == 128) ? (wave & 1) * 64 : 0;
    const int row0 = blockIdx.y * BM, col0 = blockIdx.x * BN;

    const int lrow = lane >> 2;
    const int lk = (lane & 3) * 8;

    f32x4 acc[MI][NI] = {};

    for (int k0 = 0; k0 < K; k0 += BK) {
        __syncthreads();
        for (int s = wave; s < SEGS; s += 4) {
            if (s < BM / 16) {
                gl2lds16(&A[(size_t)(row0 + s * 16 + lrow) * K + k0 + lk],
                         &As[s * 16 * BK]);
            } else {
                int t = s - BM / 16;
                gl2lds16(&Bm[(size_t)(col0 + t * 16 + lrow) * K + k0 + lk],
                         &Bs[t * 16 * BK]);
            }
        }
        __asm__ volatile("s_waitcnt vmcnt(0)" ::: "memory");
        __syncthreads();

        bf16x8 af[MI], bfr[NI];
        #pragma unroll
        for (int mi = 0; mi < MI; ++mi)
            af[mi] = *(const bf16x8*)&As[(wrow + mi * 16 + m16) * BK + quad * 8];
        #pragma unroll
        for (int ni = 0; ni < NI; ++ni)
            bfr[ni] = *(const bf16x8*)&Bs[(wcol + ni * 16 + m16) * BK + quad * 8];
        #pragma unroll
        for (int mi = 0; mi < MI; ++mi)
            #pragma unroll
            for (int ni = 0; ni < NI; ++ni)
                acc[mi][ni] = MFMA32(af[mi], bfr[ni], acc[mi][ni]);
    }

    #pragma unroll
    for (int mi = 0; mi < MI; ++mi) {
        #pragma unroll
        for (int r = 0; r < 4; ++r) {
            size_t grow = row0 + wrow + mi * 16 + quad * 4 + r;
            #pragma unroll
            for (int ni = 0; ni < NI; ++ni) {
                size_t gcol = col0 + wcol + ni * 16 + m16;
                if (c_bf16)
                    ((unsigned short*)Cout)[grow * N + gcol] = f2bf(acc[mi][ni][r]);
                else
                    ((float*)Cout)[grow * N + gcol] = acc[mi][ni][r];
            }
        }
    }
}

// ---------------------------------------------------------------------------
// MFMA flash attention. K fragments loaded DIRECTLY from global (L2-resident
// via XCD swizzle) -- no K LDS round-trip. V-only LDS, transposed+swizzled,
// double-buffered. Fixed-max softmax, lsum via ones-MFMA.
// Block: 256 thr, 64 queries (16/wave). K-tile = 64 keys. grid 1024 1D:
// bh = ((id>>3)&3)*8 + (id&7), q0 = (id>>5)*64  -> id%8 const per (b,h).
// ---------------------------------------------------------------------------
__global__ __launch_bounds__(256) void attn_mfma(const unsigned short* __restrict__ qkv,
                                                 unsigned short* __restrict__ out) {
    constexpr int LDK = 72;
    __shared__ unsigned short Vt[2][64 * LDK];  // [hd][key ^ swizzle]

    const int id = blockIdx.x;
    const int bh = ((id >> 3) & 3) * 8 + (id & 7);
    const int b = bh >> 4, h = bh & 15;
    const int q0 = (id >> 5) * 64;

    const int tid = threadIdx.x;
    const int wave = tid >> 6, lane = tid & 63;
    const int m16 = lane & 15, quad = lane >> 4;

    const float C1 = 0.125f * 1.44269504089f;   // scale * log2(e)
    const float C2 = 10.0f * 1.44269504089f;    // fixed max shift (exact)

    const unsigned short* qrow =
        qkv + ((size_t)b * S_ + q0 + wave * 16 + m16) * (3 * D_) + h * HD_;
    bf16x8 qf0 = *(const bf16x8*)(qrow + quad * 8);
    bf16x8 qf1 = *(const bf16x8*)(qrow + 32 + quad * 8);

    f32x4 o[4] = {};
    f32x4 ol = {0.f, 0.f, 0.f, 0.f};
    const bf16x4 onesf = {(short)0x3F80, (short)0x3F80, (short)0x3F80, (short)0x3F80};

    const unsigned short* kbase = qkv + (size_t)b * S_ * 3 * D_ + D_ + h * HD_;
    const unsigned short* vbase = qkv + (size_t)b * S_ * 3 * D_ + 2 * D_ + h * HD_;

    // per-lane K fragment base: row = m16, hd offset = quad*8
    const unsigned short* kfp = kbase + (size_t)m16 * (3 * D_) + quad * 8;

    // V staging indices (loop-invariant)
    const int vrp = (tid >> 4) * 2;      // V row pair (i=0); +32 for i=1
    const int vc4 = (tid & 15) * 4;      // V dim offset
    const int vxr = 4 * ((tid & 15) & 7);

    // Vt fragment addresses (relative, loop-invariant)
    int vaddr[4][4];
    #pragma unroll
    for (int dt = 0; dt < 4; ++dt) {
        int d = dt * 16 + m16;
        int xr = 4 * ((d >> 2) & 7);
        #pragma unroll
        for (int nt = 0; nt < 4; ++nt)
            vaddr[dt][nt] = d * LDK + ((nt * 16 + quad * 4) ^ xr);
    }

    ushort4 vg[2][2];

    // preload + store V tile 0 into buf 0
    #pragma unroll
    for (int i = 0; i < 2; ++i) {
        vg[i][0] = *(const ushort4*)(vbase + (size_t)(vrp + i * 32) * 3 * D_ + vc4);
        vg[i][1] = *(const ushort4*)(vbase + (size_t)(vrp + i * 32 + 1) * 3 * D_ + vc4);
    }
    #pragma unroll
    for (int i = 0; i < 2; ++i) {
        int koff = (vrp + i * 32) ^ vxr;
        *(unsigned*)&Vt[0][(vc4 + 0) * LDK + koff] = (unsigned)vg[i][0].x | ((unsigned)vg[i][1].x << 16);
        *(unsigned*)&Vt[0][(vc4 + 1) * LDK + koff] = (unsigned)vg[i][0].y | ((unsigned)vg[i][1].y << 16);
        *(unsigned*)&Vt[0][(vc4 + 2) * LDK + koff] = (unsigned)vg[i][0].z | ((unsigned)vg[i][1].z << 16);
        *(unsigned*)&Vt[0][(vc4 + 3) * LDK + koff] = (unsigned)vg[i][0].w | ((unsigned)vg[i][1].w << 16);
    }
    __syncthreads();

    for (int t = 0; t < S_ / 64; ++t) {
        const int buf = t & 1;
        const bool more = (t + 1) < (S_ / 64);

        // K fragments for THIS tile straight from global (L2 hit)
        uint4 kf[8];
        #pragma unroll
        for (int nt = 0; nt < 4; ++nt) {
            const unsigned short* kp = kfp + (size_t)(t * 64 + nt * 16) * (3 * D_);
            kf[nt * 2 + 0] = *(const uint4*)kp;
            kf[nt * 2 + 1] = *(const uint4*)(kp + 32);
        }

        // prefetch next V tile (global loads in flight during compute)
        if (more) {
            const size_t kt1 = (size_t)(t + 1) * 64;
            #pragma unroll
            for (int i = 0; i < 2; ++i) {
                vg[i][0] = *(const ushort4*)(vbase + (kt1 + vrp + i * 32) * 3 * D_ + vc4);
                vg[i][1] = *(const ushort4*)(vbase + (kt1 + vrp + i * 32 + 1) * 3 * D_ + vc4);
            }
        }

        // S^T = K·Q^T, p = exp2(z*C1 - C2), pack into K=16 A-frags
        bf16x4 pf[4];
        #pragma unroll
        for (int nt = 0; nt < 4; ++nt) {
            bf16x8 kf0, kf1;
            __builtin_memcpy(&kf0, &kf[nt * 2 + 0], 16);
            __builtin_memcpy(&kf1, &kf[nt * 2 + 1], 16);
            f32x4 z = {0.f, 0.f, 0.f, 0.f};
            z = MFMA32(kf0, qf0, z);
            z = MFMA32(kf1, qf1, z);
            float p0 = __builtin_amdgcn_exp2f(z[0] * C1 - C2);
            float p1 = __builtin_amdgcn_exp2f(z[1] * C1 - C2);
            float p2 = __builtin_amdgcn_exp2f(z[2] * C1 - C2);
            float p3 = __builtin_amdgcn_exp2f(z[3] * C1 - C2);
            union { unsigned u[2]; bf16x4 v; } pk;
            pk.u[0] = pk2bf(p0, p1);
            pk.u[1] = pk2bf(p2, p3);
            pf[nt] = pk.v;
            // row-sum of the SAME rounded p used in PV -> consistent normalization
            ol = MFMA16(pf[nt], onesf, ol);
        }

        // O += P·V via 16x16x16 (P straight from registers)
        #pragma unroll
        for (int nt = 0; nt < 4; ++nt)
            #pragma unroll
            for (int dt = 0; dt < 4; ++dt) {
                bf16x4 vf = *(const bf16x4*)&Vt[buf][vaddr[dt][nt]];
                o[dt] = MFMA16(pf[nt], vf, o[dt]);
            }

        // store prefetched V tile into the other buffer
        if (more) {
            #pragma unroll
            for (int i = 0; i < 2; ++i) {
                int koff = (vrp + i * 32) ^ vxr;
                *(unsigned*)&Vt[buf ^ 1][(vc4 + 0) * LDK + koff] = (unsigned)vg[i][0].x | ((unsigned)vg[i][1].x << 16);
                *(unsigned*)&Vt[buf ^ 1][(vc4 + 1) * LDK + koff] = (unsigned)vg[i][0].y | ((unsigned)vg[i][1].y << 16);
                *(unsigned*)&Vt[buf ^ 1][(vc4 + 2) * LDK + koff] = (unsigned)vg[i][0].z | ((unsigned)vg[i][1].z << 16);
                *(unsigned*)&Vt[buf ^ 1][(vc4 + 3) * LDK + koff] = (unsigned)vg[i][0].w | ((unsigned)vg[i][1].w << 16);
            }
        }
        __syncthreads();
    }

    // epilogue: ol[r] holds the row-sum replicated across all 16 cols
    #pragma unroll
    for (int r = 0; r < 4; ++r) {
        float inv = 1.f / ol[r];
        size_t row = (size_t)b * S_ + q0 + wave * 16 + quad * 4 + r;
        unsigned short* op = out + row * D_ + h * HD_;
        #pragma unroll
        for (int dt = 0; dt < 4; ++dt)
            op[dt * 16 + m16] = f2bf(o[dt][r] * inv);
    }
}

// ---------------------------------------------------------------------------
extern "C" void kernel_launch(void* const* d_in, const int* in_sizes, int n_in,
                              void* d_out, int out_size, void* d_ws, size_t ws_size,
                              hipStream_t stream) {
    const float* x     = (const float*)d_in[0];
    const float* w_qkv = (const float*)d_in[1];
    const float* w_out = (const float*)d_in[2];
    float* out = (float*)d_out;

    const size_t n_x = (size_t)B_ * S_ * D_;
    const size_t n_wqkv = (size_t)3 * D_ * D_;
    const size_t n_wout = (size_t)D_ * D_;

    unsigned short* xb    = (unsigned short*)d_ws;
    unsigned short* wqkvb = xb + n_x;
    unsigned short* woutb = wqkvb + n_wqkv;
    unsigned short* qkvb  = woutb + n_wout;
    unsigned short* attnb = qkvb + (size_t)B_ * S_ * 3 * D_;

    dim3 blk(256);

    cvt_all<<<2048, blk, 0, stream>>>(x, w_qkv, w_out, xb, wqkvb, woutb);

    // qkv = x @ w_qkv^T : M=4096, N=3072, K=1024 (bf16 out)
    gemm_nt_b<128><<<dim3(3 * D_ / 128, B_ * S_ / 128), blk, 0, stream>>>(
        xb, wqkvb, qkvb, B_ * S_, 3 * D_, D_, 1);

    // attention: 1024 XCD-swizzled blocks of 64 queries
    attn_mfma<<<1024, blk, 0, stream>>>(qkvb, attnb);

    // out = attn_out @ w_out^T : M=4096, N=1024, K=1024 (fp32 out, BN=64)
    gemm_nt_b<64><<<dim3(D_ / 64, B_ * S_ / 128), blk, 0, stream>>>(
        attnb, woutb, out, B_ * S_, D_, D_, 0);
}